// Round 7
// baseline (519.554 us; speedup 1.0000x reference)
//
#include <hip/hip_runtime.h>
#include <hip/hip_cooperative_groups.h>
#include <math.h>

namespace cg = cooperative_groups;

// Geometric BA (LM) — 4 iterations, B=8, N=131072.
// Round 6 resubmit (previous bench: GPU-acquisition timeout, no data).
// Cooperative single kernel, made un-rejectable (256 blocks x 512
// thr = 1 block/CU co-residency, guaranteed by __launch_bounds__(512,2)),
// PLUS a checked fallback to the proven round-3 9-dispatch path if
// hipLaunchCooperativeKernel returns an error (round-5 failure signature was
// all-zero output => launch rejected, error unchecked).
//
// Coop structure: per iter {accept-prologue, phaseA+54-red, grid.sync,
// solve-prologue (redundant/block), phaseB+3-red, grid.sync}; final accept +
// output. Disp state in registers. Reduction orders bit-identical per block;
// block count per batch is 32 (vs 64 in fallback) so partial-sum grouping
// differs from round 3 only in the final deterministic tree (absmax headroom
// 0.0625 << 0.2 in round 3).

constexpr int NRED = 54;   // Bm(21) + g(6) + Hsc(21) + bsc(6)

// ---- coop config ----
constexpr int CT   = 512;  // threads/block
constexpr int CBPB = 32;   // blocks per batch (grid = 8*32 = 256)
constexpr int CPPT = 8;    // points per thread: 32*512*8 = 131072

// ---- fallback config (round-3 verbatim) ----
constexpr int TPB  = 256;
constexpr int BLKA = 64;

__device__ __forceinline__ float wave_red(float v) {
#pragma unroll
  for (int m = 32; m; m >>= 1) v += __shfl_xor(v, m, 64);
  return v;
}

__device__ __forceinline__ float reproj_norm(
    float x1, float y1, float x2, float y2, float d,
    const float* P, const float* Kc, const float* Ki) {
  float depth = 1.0f / fmaxf(d, 0.01f);
  float pxx = (Ki[0]*x1 + Ki[1]*y1 + Ki[2]) * depth;
  float pyy = (Ki[3]*x1 + Ki[4]*y1 + Ki[5]) * depth;
  float pzz = (Ki[6]*x1 + Ki[7]*y1 + Ki[8]) * depth;
  float X = P[0]*pxx + P[1]*pyy + P[2]*pzz + P[3];
  float Y = P[4]*pxx + P[5]*pyy + P[6]*pzz + P[7];
  float Z = P[8]*pxx + P[9]*pyy + P[10]*pzz + P[11];
  float q0 = Kc[0]*X + Kc[1]*Y + Kc[2]*Z;
  float q1 = Kc[3]*X + Kc[4]*Y + Kc[5]*Z;
  float q2 = Kc[6]*X + Kc[7]*Y + Kc[8]*Z;
  float iZc = 1.0f / fmaxf(q2, 0.01f);
  float ex = x2 - q0*iZc, ey = y2 - q1*iZc;
  return sqrtf(ex*ex + ey*ey);
}

__device__ __forceinline__ void pointA(
    float x1, float y1, float x2, float y2, float m, float d,
    const float* P, const float* Kc, const float* Ki,
    float fx, float fy, float onepL, float* acc) {
  float depth = 1.0f / d;
  float pxx = (Ki[0]*x1 + Ki[1]*y1 + Ki[2]) * depth;
  float pyy = (Ki[3]*x1 + Ki[4]*y1 + Ki[5]) * depth;
  float pzz = (Ki[6]*x1 + Ki[7]*y1 + Ki[8]) * depth;
  float X = P[0]*pxx + P[1]*pyy + P[2]*pzz + P[3];
  float Y = P[4]*pxx + P[5]*pyy + P[6]*pzz + P[7];
  float Z = P[8]*pxx + P[9]*pyy + P[10]*pzz + P[11];
  float q0 = Kc[0]*X + Kc[1]*Y + Kc[2]*Z;
  float q1 = Kc[3]*X + Kc[4]*Y + Kc[5]*Z;
  float q2 = Kc[6]*X + Kc[7]*Y + Kc[8]*Z;
  float iZc = 1.0f / fmaxf(q2, 0.01f);
  float ex = x2 - q0*iZc;
  float ey = y2 - q1*iZc;
  float iZ = 1.0f / fmaxf(Z, 1e-12f);
  float iZ2 = iZ*iZ;

  float jp0[6], jp1[6];
  jp0[0] = -(fx*iZ);  jp0[1] = 0.0f;       jp0[2] = fx*X*iZ2;
  jp0[3] = fx*X*Y*iZ2; jp0[4] = -(fx + fx*X*X*iZ2); jp0[5] = fx*Y*iZ;
  jp1[0] = 0.0f;      jp1[1] = -(fy*iZ);   jp1[2] = fy*Y*iZ2;
  jp1[3] = fy + fy*Y*Y*iZ2; jp1[4] = -(fy*X*Y*iZ2); jp1[5] = -(fy*X*iZ);

  float DD = -depth;
  float dx = X - P[3], dy = Y - P[7], dz = Z - P[11];
  float jd0 = -((fx*iZ)*(DD*dx) - (fx*X*iZ2)*(DD*dz));
  float jd1 = -((fy*iZ)*(DD*dy) - (fy*Y*iZ2)*(DD*dz));

  float en = sqrtf(ex*ex + ey*ey);
  float wmin = fminf(9.0f / fmaxf(en, 1e-12f), 1.0f);
  float w  = sqrtf(wmin) * m;
  float w2 = w * w;

  float E[6];
#pragma unroll
  for (int k = 0; k < 6; k++) E[k] = w2*(jp0[k]*jd0 + jp1[k]*jd1);
  float C = w2*(jd0*jd0 + jd1*jd1);
  float cinv = 1.0f / fmaxf(C*onepL, 1.0f);
  float Wv = -w*(jd0*ex + jd1*ey);

  int idx = 0;
#pragma unroll
  for (int k = 0; k < 6; k++)
#pragma unroll
    for (int l = k; l < 6; l++) { acc[idx] += w2*(jp0[k]*jp0[l] + jp1[k]*jp1[l]); idx++; }
#pragma unroll
  for (int k = 0; k < 6; k++) acc[21+k] -= w*(jp0[k]*ex + jp1[k]*ey);
  idx = 27;
#pragma unroll
  for (int k = 0; k < 6; k++)
#pragma unroll
    for (int l = k; l < 6; l++) { acc[idx] += (cinv*E[k])*E[l]; idx++; }
#pragma unroll
  for (int k = 0; k < 6; k++) acc[48+k] += cinv*E[k]*Wv;
}

__device__ __forceinline__ float pointB(
    float x1, float y1, float x2, float y2, float m, float d,
    const float* P, const float* Pn, const float* dp,
    const float* Kc, const float* Ki,
    float fx, float fy, float onepL, float invL,
    float& r1a, float& r2a, float& msa) {
  float depth = 1.0f / d;
  float pxx = (Ki[0]*x1 + Ki[1]*y1 + Ki[2]) * depth;
  float pyy = (Ki[3]*x1 + Ki[4]*y1 + Ki[5]) * depth;
  float pzz = (Ki[6]*x1 + Ki[7]*y1 + Ki[8]) * depth;
  float X = P[0]*pxx + P[1]*pyy + P[2]*pzz + P[3];
  float Y = P[4]*pxx + P[5]*pyy + P[6]*pzz + P[7];
  float Z = P[8]*pxx + P[9]*pyy + P[10]*pzz + P[11];
  float q0 = Kc[0]*X + Kc[1]*Y + Kc[2]*Z;
  float q1 = Kc[3]*X + Kc[4]*Y + Kc[5]*Z;
  float q2 = Kc[6]*X + Kc[7]*Y + Kc[8]*Z;
  float iZc = 1.0f / fmaxf(q2, 0.01f);
  float ex = x2 - q0*iZc;
  float ey = y2 - q1*iZc;
  float iZ = 1.0f / fmaxf(Z, 1e-12f);
  float iZ2 = iZ*iZ;

  float jp0[6], jp1[6];
  jp0[0] = -(fx*iZ);  jp0[1] = 0.0f;       jp0[2] = fx*X*iZ2;
  jp0[3] = fx*X*Y*iZ2; jp0[4] = -(fx + fx*X*X*iZ2); jp0[5] = fx*Y*iZ;
  jp1[0] = 0.0f;      jp1[1] = -(fy*iZ);   jp1[2] = fy*Y*iZ2;
  jp1[3] = fy + fy*Y*Y*iZ2; jp1[4] = -(fy*X*Y*iZ2); jp1[5] = -(fy*X*iZ);

  float DD = -depth;
  float dx = X - P[3], dy = Y - P[7], dz = Z - P[11];
  float jd0 = -((fx*iZ)*(DD*dx) - (fx*X*iZ2)*(DD*dz));
  float jd1 = -((fy*iZ)*(DD*dy) - (fy*Y*iZ2)*(DD*dz));

  float en = sqrtf(ex*ex + ey*ey);
  float wmin = fminf(9.0f / fmaxf(en, 1e-12f), 1.0f);
  float w  = sqrtf(wmin) * m;
  float w2 = w * w;

  float dotE = 0.0f;
#pragma unroll
  for (int k = 0; k < 6; k++) {
    float Ek = w2*(jp0[k]*jd0 + jp1[k]*jd1);
    dotE += Ek * dp[k];
  }
  float C = w2*(jd0*jd0 + jd1*jd1);
  float cinv = 1.0f / fmaxf(C*onepL, 1.0f);
  float Wv = -w*(jd0*ex + jd1*ey);

  float dnew = d + cinv*(Wv - dotE*invL);
  dnew = fminf(fmaxf(dnew, 0.01f), 10.0f);

  float n1 = reproj_norm(x1, y1, x2, y2, dnew, Pn, Kc, Ki);
  float n2 = reproj_norm(x1, y1, x2, y2, d,    P,  Kc, Ki);
  r1a += n1*m; r2a += n2*m; msa += m;
  return dnew;
}

// solve: 54 sums -> dp[6] + pose_new[16]. Runs on one thread.
__device__ void solve_scalar(const float* S, float L, const float* Pc_in,
                             float invN, float* dp_out, float* Pn_out) {
  float Bm[6][6], Hs[6][6], g[6], bs[6];
  {
    int idx = 0;
    for (int k = 0; k < 6; k++)
      for (int l = k; l < 6; l++) { float v = S[idx++]*invN; Bm[k][l] = v; Bm[l][k] = v; }
    for (int k = 0; k < 6; k++) g[k] = S[21+k]*invN;
    idx = 27;
    for (int k = 0; k < 6; k++)
      for (int l = k; l < 6; l++) { float v = S[idx++]*invN; Hs[k][l] = v; Hs[l][k] = v; }
    for (int k = 0; k < 6; k++) bs[k] = S[48+k]*invN;
  }
  const float invL = 1.0f / (1.0f + L);
  float left[6][6], right[6];
  for (int k = 0; k < 6; k++) {
    for (int l = 0; l < 6; l++) {
      float v = Bm[k][l] - Hs[k][l]*invL;
      if (k == l) v += Bm[k][k]*L + 1.0f;
      left[k][l] = v;
    }
    right[k] = g[k] - bs[k]*invL;
  }
  float sv[6];
  for (int k = 0; k < 6; k++) sv[k] = 1.0f / sqrtf(left[k][k] + 10.0f);
  float H[6][7];
  for (int k = 0; k < 6; k++) {
    for (int l = 0; l < 6; l++) H[k][l] = sv[k]*left[k][l]*sv[l];
    H[k][6] = sv[k]*right[k];
  }
  for (int c = 0; c < 6; c++) {
    int piv = c; float mx = fabsf(H[c][c]);
    for (int r = c+1; r < 6; r++) { float a = fabsf(H[r][c]); if (a > mx) { mx = a; piv = r; } }
    if (piv != c)
      for (int cc2 = c; cc2 < 7; cc2++) { float tmp = H[c][cc2]; H[c][cc2] = H[piv][cc2]; H[piv][cc2] = tmp; }
    float ip = 1.0f / H[c][c];
    for (int r = c+1; r < 6; r++) {
      float f = H[r][c]*ip;
      for (int cc2 = c; cc2 < 7; cc2++) H[r][cc2] -= f*H[c][cc2];
    }
  }
  float x[6];
  for (int c = 5; c >= 0; c--) {
    float v = H[c][6];
    for (int cc2 = c+1; cc2 < 6; cc2++) v -= H[c][cc2]*x[cc2];
    x[c] = v / H[c][c];
  }
  float dp[6];
  for (int k = 0; k < 6; k++) { dp[k] = sv[k]*x[k]; dp_out[k] = dp[k]; }

  float tx = dp[0], ty = dp[1], tz = dp[2];
  float wx = dp[3], wy = dp[4], wz = dp[5];
  float Nr = fmaxf(sqrtf(wx*wx + wy*wy + wz*wz), 1e-12f);
  float rx = wx/Nr, ry = wy/Nr, rz = wz/Nr;
  float c_ = cosf(Nr), sn = sinf(Nr);
  float omc = 1.0f - c_;
  float SK[3][3] = {{0.0f,-rz,ry},{rz,0.0f,-rx},{-ry,rx,0.0f}};
  float SK2[3][3];
  for (int i = 0; i < 3; i++)
    for (int j2 = 0; j2 < 3; j2++) {
      float s2 = 0.0f;
      for (int k = 0; k < 3; k++) s2 += SK[i][k]*SK[k][j2];
      SK2[i][j2] = s2;
    }
  float rr[3] = {rx, ry, rz};
  float a = (Nr - sn)/Nr, bcoef = omc/Nr;
  float R3[3][3], Jm[3][3];
  for (int i = 0; i < 3; i++)
    for (int j2 = 0; j2 < 3; j2++) {
      float eye = (i == j2) ? 1.0f : 0.0f;
      R3[i][j2] = c_*eye + omc*rr[i]*rr[j2] + sn*SK[i][j2];
      Jm[i][j2] = eye + a*SK2[i][j2] + bcoef*SK[i][j2];
    }
  float T3[3];
  for (int i = 0; i < 3; i++) T3[i] = Jm[i][0]*tx + Jm[i][1]*ty + Jm[i][2]*tz;
  for (int i = 0; i < 3; i++)
    for (int j2 = 0; j2 < 4; j2++)
      Pn_out[i*4+j2] = R3[i][0]*Pc_in[j2] + R3[i][1]*Pc_in[4+j2] + R3[i][2]*Pc_in[8+j2] + T3[i]*Pc_in[12+j2];
  for (int j2 = 0; j2 < 4; j2++) Pn_out[12+j2] = Pc_in[12+j2];
}

// =================== cooperative single kernel ===================
__global__ __launch_bounds__(CT, 2) void kCoop(
    const float* __restrict__ pts, const float* __restrict__ disp0,
    const float* __restrict__ mask, const float* __restrict__ Kin,
    const float* __restrict__ Kiin, const float* __restrict__ pose0,
    const float* __restrict__ L0,
    float* __restrict__ partA, float* __restrict__ partB,
    float* __restrict__ dout, int N, int B) {
  cg::grid_group grid = cg::this_grid();
  const int b   = blockIdx.x / CBPB;
  const int bx  = blockIdx.x % CBPB;
  const int tid = threadIdx.x;
  const int lane = tid & 63, wvi = tid >> 6;

  __shared__ float sP[16];
  __shared__ float sPn[16];
  __shared__ float sdp[6];
  __shared__ float sS[NRED];
  __shared__ float sMeta[2]; // [0]=M, [1]=L
  __shared__ float lds54[CT/64][NRED];
  __shared__ float lds3[CT/64][3];

  float Kc[9], Ki[9];
#pragma unroll
  for (int i = 0; i < 9; i++) { Kc[i] = Kin[b*9+i]; Ki[i] = Kiin[b*9+i]; }
  const float fx = Kc[0], fy = Kc[4];

  if (tid == 0) {
#pragma unroll
    for (int i = 0; i < 16; i++) sP[i] = pose0[b*16+i];
    sMeta[0] = 0.0f; sMeta[1] = L0[b];
  }
  __syncthreads();

  const size_t bN = (size_t)b * N;
  const float* px1 = pts + (size_t)b*4*N;
  const float* py1 = px1 + N;
  const float* px2 = px1 + 2*(size_t)N;
  const float* py2 = px1 + 3*(size_t)N;
  const int n0 = bx*CT + tid;
  constexpr int STRIDE = CBPB*CT;

  float d[CPPT], dn[CPPT];
#pragma unroll
  for (int j = 0; j < CPPT; j++) {
    int n = n0 + j*STRIDE;
    d[j]  = (n < N) ? disp0[bN+n] : 1.0f;
    dn[j] = d[j];
  }

  for (int it = 0; it < 4; ++it) {
    if (it > 0) {
      if (tid == 0) {
        float r1 = 0.0f, r2 = 0.0f, ms = 0.0f;
        for (int j = 0; j < CBPB; j++) {
          const float* p = partB + ((size_t)b*CBPB + j)*3;
          r1 += p[0]; r2 += p[1]; ms += p[2];
        }
        float M = ((r1/ms) < (r2/ms)) ? 1.0f : 0.0f;
        sMeta[0] = M;
        float Lp = sMeta[1];
        float Ln = (M != 0.0f) ? Lp*0.5f : Lp*5.0f;
        sMeta[1] = fminf(fmaxf(Ln, 0.01f), 1000000.0f);
        if (M != 0.0f)
          for (int i = 0; i < 16; i++) sP[i] = sPn[i];
      }
      __syncthreads();
      if (sMeta[0] != 0.0f) {
#pragma unroll
        for (int j = 0; j < CPPT; j++) d[j] = dn[j];
      }
    }
    const float onepL = 1.0f + sMeta[1];
    float P[12];
#pragma unroll
    for (int i = 0; i < 12; i++) P[i] = sP[i];

    // phase A
    float acc[NRED];
#pragma unroll
    for (int k = 0; k < NRED; k++) acc[k] = 0.0f;
#pragma unroll
    for (int j = 0; j < CPPT; j++) {
      int n = n0 + j*STRIDE;
      float x1 = 0.0f, y1 = 0.0f, x2 = 0.0f, y2 = 0.0f, m = 0.0f;
      if (n < N) { x1 = px1[n]; y1 = py1[n]; x2 = px2[n]; y2 = py2[n]; m = mask[bN+n]; }
      pointA(x1, y1, x2, y2, m, d[j], P, Kc, Ki, fx, fy, onepL, acc);
    }
#pragma unroll
    for (int k = 0; k < NRED; k++) {
      float v = wave_red(acc[k]);
      if (lane == 0) lds54[wvi][k] = v;
    }
    __syncthreads();
    if (tid < NRED) {
      float s = 0.0f;
#pragma unroll
      for (int wq = 0; wq < CT/64; wq++) s += lds54[wq][tid];
      partA[((size_t)b*CBPB + bx)*NRED + tid] = s;
    }
    grid.sync();

    // solve prologue (redundant per block)
    if (tid < NRED) {
      float s = 0.0f;
      for (int j = 0; j < CBPB; j++)
        s += partA[((size_t)b*CBPB + j)*NRED + tid];
      sS[tid] = s;
    }
    __syncthreads();
    if (tid == 0) {
      float dpl[6], Pnl[16], Pcl[16], Sl[NRED];
      for (int i = 0; i < NRED; i++) Sl[i] = sS[i];
      for (int i = 0; i < 16; i++) Pcl[i] = sP[i];
      solve_scalar(Sl, sMeta[1], Pcl, 1.0f / (float)N, dpl, Pnl);
      for (int i = 0; i < 6; i++) sdp[i] = dpl[i];
      for (int i = 0; i < 16; i++) sPn[i] = Pnl[i];
    }
    __syncthreads();

    // phase B
    float Pn[12], dp[6];
#pragma unroll
    for (int i = 0; i < 12; i++) Pn[i] = sPn[i];
#pragma unroll
    for (int i = 0; i < 6; i++) dp[i] = sdp[i];
    const float invL = 1.0f / onepL;

    float r1a = 0.0f, r2a = 0.0f, msa = 0.0f;
#pragma unroll
    for (int j = 0; j < CPPT; j++) {
      int n = n0 + j*STRIDE;
      float x1 = 0.0f, y1 = 0.0f, x2 = 0.0f, y2 = 0.0f, m = 0.0f;
      if (n < N) { x1 = px1[n]; y1 = py1[n]; x2 = px2[n]; y2 = py2[n]; m = mask[bN+n]; }
      dn[j] = pointB(x1, y1, x2, y2, m, d[j], P, Pn, dp, Kc, Ki,
                     fx, fy, onepL, invL, r1a, r2a, msa);
    }
    {
      float v0 = wave_red(r1a), v1 = wave_red(r2a), v2 = wave_red(msa);
      if (lane == 0) { lds3[wvi][0] = v0; lds3[wvi][1] = v1; lds3[wvi][2] = v2; }
    }
    __syncthreads();
    if (tid < 3) {
      float s = 0.0f;
#pragma unroll
      for (int wq = 0; wq < CT/64; wq++) s += lds3[wq][tid];
      partB[((size_t)b*CBPB + bx)*3 + tid] = s;
    }
    grid.sync();
  }

  // final accept + output
  if (tid == 0) {
    float r1 = 0.0f, r2 = 0.0f, ms = 0.0f;
    for (int j = 0; j < CBPB; j++) {
      const float* p = partB + ((size_t)b*CBPB + j)*3;
      r1 += p[0]; r2 += p[1]; ms += p[2];
    }
    float M = ((r1/ms) < (r2/ms)) ? 1.0f : 0.0f;
    sMeta[0] = M;
    if (M != 0.0f)
      for (int i = 0; i < 16; i++) sP[i] = sPn[i];
  }
  __syncthreads();
  const float Mf = sMeta[0];

  if (bx == 0 && tid < 16) dout[b*16 + tid] = sP[tid];
  float* dd = dout + B*16;
#pragma unroll
  for (int j = 0; j < CPPT; j++) {
    int n = n0 + j*STRIDE;
    if (n < N) dd[bN+n] = (Mf != 0.0f) ? dn[j] : d[j];
  }
}

// =================== fallback: round-3 proven 9-dispatch path ===================
__device__ __forceinline__ float accept_M_fb(const float* __restrict__ partB, int b) {
  float r1 = 0.0f, r2 = 0.0f, ms = 0.0f;
  for (int j = 0; j < BLKA; j++) {
    const float* p = partB + ((size_t)b*BLKA + j)*3;
    r1 += p[0]; r2 += p[1]; ms += p[2];
  }
  return ((r1/ms) < (r2/ms)) ? 1.0f : 0.0f;
}

__global__ __launch_bounds__(TPB) void fb_kA(
    int it,
    const float* __restrict__ pts, const float* __restrict__ disp_src,
    const float* __restrict__ prop, const float* __restrict__ mask,
    const float* __restrict__ Kin, const float* __restrict__ Kiin,
    float* __restrict__ disp_cur,
    const float* __restrict__ pose0, const float* __restrict__ L0,
    const float* __restrict__ partB, const float* __restrict__ pose_new_ws,
    float* __restrict__ pose_slot_w, const float* __restrict__ pose_slot_r,
    float* __restrict__ L_slot_w, const float* __restrict__ L_slot_r,
    float* __restrict__ partA, int N) {
  const int b = blockIdx.y;

  __shared__ float sP[16];
  __shared__ float sMeta[2];
  if (threadIdx.x == 0) {
    float P[16], Lv, fs;
    if (it == 0) {
      for (int i = 0; i < 16; i++) P[i] = pose0[b*16+i];
      Lv = L0[b]; fs = 0.0f;
    } else {
      float M = accept_M_fb(partB, b);
      fs = M;
      float Lp = L_slot_r[b];
      float Ln = (M != 0.0f) ? Lp*0.5f : Lp*5.0f;
      Lv = fminf(fmaxf(Ln, 0.01f), 1000000.0f);
      for (int i = 0; i < 16; i++)
        P[i] = (M != 0.0f) ? pose_new_ws[b*16+i] : pose_slot_r[b*16+i];
    }
    for (int i = 0; i < 16; i++) sP[i] = P[i];
    sMeta[0] = fs; sMeta[1] = Lv;
    if (blockIdx.x == 0) {
      for (int i = 0; i < 16; i++) pose_slot_w[b*16+i] = P[i];
      L_slot_w[b] = Lv;
    }
  }
  __syncthreads();

  float Kc[9], Ki[9], P[12];
#pragma unroll
  for (int i = 0; i < 9; i++) { Kc[i] = Kin[b*9+i]; Ki[i] = Kiin[b*9+i]; }
#pragma unroll
  for (int i = 0; i < 12; i++) P[i] = sP[i];
  const float onepL = 1.0f + sMeta[1];
  const float fsel = sMeta[0];
  const float fx = Kc[0], fy = Kc[4];

  float acc[NRED];
#pragma unroll
  for (int k = 0; k < NRED; k++) acc[k] = 0.0f;

  const size_t bN = (size_t)b * N;
  const float* px1 = pts + (size_t)b*4*N;
  const float* py1 = px1 + N;
  const float* px2 = px1 + 2*(size_t)N;
  const float* py2 = px1 + 3*(size_t)N;

  for (int n = blockIdx.x*TPB + threadIdx.x; n < N; n += gridDim.x*TPB) {
    float x1 = px1[n], y1 = py1[n], x2 = px2[n], y2 = py2[n];
    float d = disp_src[bN+n];
    if (fsel != 0.0f) d = prop[bN+n];
    disp_cur[bN+n] = d;
    float m = mask[bN+n];
    pointA(x1, y1, x2, y2, m, d, P, Kc, Ki, fx, fy, onepL, acc);
  }

  __shared__ float lds[TPB/64][NRED];
  const int lane = threadIdx.x & 63, wvi = threadIdx.x >> 6;
#pragma unroll
  for (int k = 0; k < NRED; k++) {
    float v = wave_red(acc[k]);
    if (lane == 0) lds[wvi][k] = v;
  }
  __syncthreads();
  if (threadIdx.x < NRED) {
    float s = 0.0f;
#pragma unroll
    for (int wq = 0; wq < TPB/64; wq++) s += lds[wq][threadIdx.x];
    partA[((size_t)b*gridDim.x + blockIdx.x)*NRED + threadIdx.x] = s;
  }
}

__global__ __launch_bounds__(TPB) void fb_kB(
    const float* __restrict__ pts, const float* __restrict__ disp_cur,
    const float* __restrict__ mask,
    const float* __restrict__ Kin, const float* __restrict__ Kiin,
    const float* __restrict__ pose_slot, const float* __restrict__ L_slot,
    const float* __restrict__ partA,
    float* __restrict__ pose_new_ws,
    float* __restrict__ prop, float* __restrict__ partB, int N) {
  const int b = blockIdx.y;
  const float L = L_slot[b];

  __shared__ float S[NRED];
  __shared__ float sPn[16];
  __shared__ float sdp[6];
  if (threadIdx.x < NRED) {
    float s = 0.0f;
    for (int j = 0; j < BLKA; j++)
      s += partA[((size_t)b*BLKA + j)*NRED + threadIdx.x];
    S[threadIdx.x] = s;
  }
  __syncthreads();
  if (threadIdx.x == 0) {
    float dpl[6], Pnl[16], Pcl[16], Sl[NRED];
    for (int i = 0; i < NRED; i++) Sl[i] = S[i];
    for (int i = 0; i < 16; i++) Pcl[i] = pose_slot[b*16+i];
    solve_scalar(Sl, L, Pcl, 1.0f / (float)N, dpl, Pnl);
    for (int i = 0; i < 6; i++) sdp[i] = dpl[i];
    for (int i = 0; i < 16; i++) sPn[i] = Pnl[i];
    if (blockIdx.x == 0)
      for (int i = 0; i < 16; i++) pose_new_ws[b*16+i] = Pnl[i];
  }
  __syncthreads();

  float Kc[9], Ki[9], P[12], Pn[12], dp[6];
#pragma unroll
  for (int i = 0; i < 9; i++) { Kc[i] = Kin[b*9+i]; Ki[i] = Kiin[b*9+i]; }
#pragma unroll
  for (int i = 0; i < 12; i++) { P[i] = pose_slot[b*16+i]; Pn[i] = sPn[i]; }
#pragma unroll
  for (int i = 0; i < 6; i++) dp[i] = sdp[i];
  const float onepL = 1.0f + L;
  const float invL = 1.0f / onepL;
  const float fx = Kc[0], fy = Kc[4];

  float r1a = 0.0f, r2a = 0.0f, msa = 0.0f;
  const size_t bN = (size_t)b * N;
  const float* px1 = pts + (size_t)b*4*N;
  const float* py1 = px1 + N;
  const float* px2 = px1 + 2*(size_t)N;
  const float* py2 = px1 + 3*(size_t)N;

  for (int n = blockIdx.x*TPB + threadIdx.x; n < N; n += gridDim.x*TPB) {
    float x1 = px1[n], y1 = py1[n], x2 = px2[n], y2 = py2[n];
    float d = disp_cur[bN+n];
    float m = mask[bN+n];
    float dnew = pointB(x1, y1, x2, y2, m, d, P, Pn, dp, Kc, Ki,
                        fx, fy, onepL, invL, r1a, r2a, msa);
    prop[bN+n] = dnew;
  }

  __shared__ float lds[TPB/64][3];
  const int lane = threadIdx.x & 63, wvi = threadIdx.x >> 6;
  float v0 = wave_red(r1a), v1 = wave_red(r2a), v2 = wave_red(msa);
  if (lane == 0) { lds[wvi][0] = v0; lds[wvi][1] = v1; lds[wvi][2] = v2; }
  __syncthreads();
  if (threadIdx.x < 3) {
    float s = 0.0f;
#pragma unroll
    for (int wq = 0; wq < TPB/64; wq++) s += lds[wq][threadIdx.x];
    partB[((size_t)b*gridDim.x + blockIdx.x)*3 + threadIdx.x] = s;
  }
}

__global__ __launch_bounds__(TPB) void fb_kF(
    const float* __restrict__ partB,
    const float* __restrict__ pose_slot, const float* __restrict__ pose_new_ws,
    const float* __restrict__ prop, float* __restrict__ dout, int N, int B) {
  const int b = blockIdx.y;
  __shared__ float sM[1];
  if (threadIdx.x == 0) sM[0] = accept_M_fb(partB, b);
  __syncthreads();
  const float M = sM[0];

  if (blockIdx.x == 0 && threadIdx.x < 16) {
    float v = (M != 0.0f) ? pose_new_ws[b*16+threadIdx.x] : pose_slot[b*16+threadIdx.x];
    dout[b*16 + threadIdx.x] = v;
  }
  if (M == 0.0f) return;
  float* dd = dout + B*16;
  const size_t bN = (size_t)b * N;
  for (int n = blockIdx.x*TPB + threadIdx.x; n < N; n += gridDim.x*TPB)
    dd[bN+n] = prop[bN+n];
}

extern "C" void kernel_launch(void* const* d_in, const int* in_sizes, int n_in,
                              void* d_out, int out_size, void* d_ws, size_t ws_size,
                              hipStream_t stream) {
  const float* pts   = (const float*)d_in[0];
  const float* disp0 = (const float*)d_in[1];
  const float* pose0 = (const float*)d_in[2];
  const float* Kin   = (const float*)d_in[3];
  const float* Kiin  = (const float*)d_in[4];
  const float* mask  = (const float*)d_in[5];
  const float* L0    = (const float*)d_in[6];

  const int B = in_sizes[6];            // 8
  const int N = in_sizes[1] / B;        // 131072
  const size_t BN = (size_t)B * N;

  float* out      = (float*)d_out;
  float* disp_cur = out + B*16;

  // ws layout: fallback region first, coop region after (disjoint).
  float* ws        = (float*)d_ws;
  float* prop      = ws;                                   // BN
  float* partA_fb  = prop + BN;                            // B*BLKA*NRED
  float* partB_fb  = partA_fb + (size_t)B*BLKA*NRED;       // B*BLKA*3
  float* pose_slots= partB_fb + (size_t)B*BLKA*3;          // 2*B*16
  float* pose_new  = pose_slots + (size_t)2*B*16;          // B*16
  float* L_slots   = pose_new + (size_t)B*16;              // 2*B
  float* partA_cp  = L_slots + (size_t)2*B;                // B*CBPB*NRED
  float* partB_cp  = partA_cp + (size_t)B*CBPB*NRED;       // B*CBPB*3

  // ---- try cooperative single-kernel path ----
  void* args[] = {(void*)&pts, (void*)&disp0, (void*)&mask, (void*)&Kin,
                  (void*)&Kiin, (void*)&pose0, (void*)&L0,
                  (void*)&partA_cp, (void*)&partB_cp, (void*)&out,
                  (void*)&N, (void*)&B};
  hipError_t ce = hipLaunchCooperativeKernel((void*)kCoop, dim3(B*CBPB),
                                             dim3(CT), args, 0, stream);
  if (ce == hipSuccess) return;
  (void)hipGetLastError();   // clear latched error, run proven fallback

  dim3 gridBig(BLKA, B), blk(TPB);
  for (int it = 0; it < 4; ++it) {
    float* ps_w = pose_slots + (size_t)(it & 1) * B * 16;
    const float* ps_r = pose_slots + (size_t)((it + 1) & 1) * B * 16;
    float* Ls_w = L_slots + (size_t)(it & 1) * B;
    const float* Ls_r = L_slots + (size_t)((it + 1) & 1) * B;

    fb_kA<<<gridBig, blk, 0, stream>>>(it, pts, (it == 0) ? disp0 : disp_cur, prop,
                                       mask, Kin, Kiin, disp_cur, pose0, L0,
                                       partB_fb, pose_new, ps_w, ps_r, Ls_w, Ls_r,
                                       partA_fb, N);
    fb_kB<<<gridBig, blk, 0, stream>>>(pts, disp_cur, mask, Kin, Kiin,
                                       ps_w, Ls_w, partA_fb, pose_new,
                                       prop, partB_fb, N);
  }
  fb_kF<<<gridBig, blk, 0, stream>>>(partB_fb, pose_slots + (size_t)1*B*16,
                                     pose_new, prop, out, N, B);
}

// Round 9
// 488.992 us; speedup vs baseline: 1.0625x; 1.0625x over previous
//
#include <hip/hip_runtime.h>
#include <hip/hip_cooperative_groups.h>
#include <math.h>

namespace cg = cooperative_groups;

// Geometric BA (LM) — 4 iterations, B=8, N=131072.
// Round 8 resubmit (previous bench: GPU-acquisition timeout, no data).
// Coop kernel with REGISTER-RESIDENT POINTS. Round-7 counters showed
// kCoop latency-bound (VALUBusy 18%, FETCH 99MB, occ 24%): the 8 phases
// re-read pts/mask every phase and per-XCD L2 (4MB) can't hold them across
// grid.syncs. Fix: each thread loads its 8 points (x1,y1,x2,y2,m) ONCE into
// registers (~56 persistent VGPRs, cap 256 via __launch_bounds__(512,2));
// phases then do zero global loads except the 54/3-value partials.
// Arithmetic & reduction orders bit-identical to round-7 (passed, 0.0625).
// Checked fallback to the proven round-3 9-dispatch path retained.

constexpr int NRED = 54;   // Bm(21) + g(6) + Hsc(21) + bsc(6)

// ---- coop config ----
constexpr int CT   = 512;  // threads/block
constexpr int CBPB = 32;   // blocks per batch (grid = 8*32 = 256)
constexpr int CPPT = 8;    // points per thread: 32*512*8 = 131072

// ---- fallback config (round-3 verbatim) ----
constexpr int TPB  = 256;
constexpr int BLKA = 64;

__device__ __forceinline__ float wave_red(float v) {
#pragma unroll
  for (int m = 32; m; m >>= 1) v += __shfl_xor(v, m, 64);
  return v;
}

__device__ __forceinline__ float reproj_norm(
    float x1, float y1, float x2, float y2, float d,
    const float* P, const float* Kc, const float* Ki) {
  float depth = 1.0f / fmaxf(d, 0.01f);
  float pxx = (Ki[0]*x1 + Ki[1]*y1 + Ki[2]) * depth;
  float pyy = (Ki[3]*x1 + Ki[4]*y1 + Ki[5]) * depth;
  float pzz = (Ki[6]*x1 + Ki[7]*y1 + Ki[8]) * depth;
  float X = P[0]*pxx + P[1]*pyy + P[2]*pzz + P[3];
  float Y = P[4]*pxx + P[5]*pyy + P[6]*pzz + P[7];
  float Z = P[8]*pxx + P[9]*pyy + P[10]*pzz + P[11];
  float q0 = Kc[0]*X + Kc[1]*Y + Kc[2]*Z;
  float q1 = Kc[3]*X + Kc[4]*Y + Kc[5]*Z;
  float q2 = Kc[6]*X + Kc[7]*Y + Kc[8]*Z;
  float iZc = 1.0f / fmaxf(q2, 0.01f);
  float ex = x2 - q0*iZc, ey = y2 - q1*iZc;
  return sqrtf(ex*ex + ey*ey);
}

__device__ __forceinline__ void pointA(
    float x1, float y1, float x2, float y2, float m, float d,
    const float* P, const float* Kc, const float* Ki,
    float fx, float fy, float onepL, float* acc) {
  float depth = 1.0f / d;
  float pxx = (Ki[0]*x1 + Ki[1]*y1 + Ki[2]) * depth;
  float pyy = (Ki[3]*x1 + Ki[4]*y1 + Ki[5]) * depth;
  float pzz = (Ki[6]*x1 + Ki[7]*y1 + Ki[8]) * depth;
  float X = P[0]*pxx + P[1]*pyy + P[2]*pzz + P[3];
  float Y = P[4]*pxx + P[5]*pyy + P[6]*pzz + P[7];
  float Z = P[8]*pxx + P[9]*pyy + P[10]*pzz + P[11];
  float q0 = Kc[0]*X + Kc[1]*Y + Kc[2]*Z;
  float q1 = Kc[3]*X + Kc[4]*Y + Kc[5]*Z;
  float q2 = Kc[6]*X + Kc[7]*Y + Kc[8]*Z;
  float iZc = 1.0f / fmaxf(q2, 0.01f);
  float ex = x2 - q0*iZc;
  float ey = y2 - q1*iZc;
  float iZ = 1.0f / fmaxf(Z, 1e-12f);
  float iZ2 = iZ*iZ;

  float jp0[6], jp1[6];
  jp0[0] = -(fx*iZ);  jp0[1] = 0.0f;       jp0[2] = fx*X*iZ2;
  jp0[3] = fx*X*Y*iZ2; jp0[4] = -(fx + fx*X*X*iZ2); jp0[5] = fx*Y*iZ;
  jp1[0] = 0.0f;      jp1[1] = -(fy*iZ);   jp1[2] = fy*Y*iZ2;
  jp1[3] = fy + fy*Y*Y*iZ2; jp1[4] = -(fy*X*Y*iZ2); jp1[5] = -(fy*X*iZ);

  float DD = -depth;
  float dx = X - P[3], dy = Y - P[7], dz = Z - P[11];
  float jd0 = -((fx*iZ)*(DD*dx) - (fx*X*iZ2)*(DD*dz));
  float jd1 = -((fy*iZ)*(DD*dy) - (fy*Y*iZ2)*(DD*dz));

  float en = sqrtf(ex*ex + ey*ey);
  float wmin = fminf(9.0f / fmaxf(en, 1e-12f), 1.0f);
  float w  = sqrtf(wmin) * m;
  float w2 = w * w;

  float E[6];
#pragma unroll
  for (int k = 0; k < 6; k++) E[k] = w2*(jp0[k]*jd0 + jp1[k]*jd1);
  float C = w2*(jd0*jd0 + jd1*jd1);
  float cinv = 1.0f / fmaxf(C*onepL, 1.0f);
  float Wv = -w*(jd0*ex + jd1*ey);

  int idx = 0;
#pragma unroll
  for (int k = 0; k < 6; k++)
#pragma unroll
    for (int l = k; l < 6; l++) { acc[idx] += w2*(jp0[k]*jp0[l] + jp1[k]*jp1[l]); idx++; }
#pragma unroll
  for (int k = 0; k < 6; k++) acc[21+k] -= w*(jp0[k]*ex + jp1[k]*ey);
  idx = 27;
#pragma unroll
  for (int k = 0; k < 6; k++)
#pragma unroll
    for (int l = k; l < 6; l++) { acc[idx] += (cinv*E[k])*E[l]; idx++; }
#pragma unroll
  for (int k = 0; k < 6; k++) acc[48+k] += cinv*E[k]*Wv;
}

__device__ __forceinline__ float pointB(
    float x1, float y1, float x2, float y2, float m, float d,
    const float* P, const float* Pn, const float* dp,
    const float* Kc, const float* Ki,
    float fx, float fy, float onepL, float invL,
    float& r1a, float& r2a, float& msa) {
  float depth = 1.0f / d;
  float pxx = (Ki[0]*x1 + Ki[1]*y1 + Ki[2]) * depth;
  float pyy = (Ki[3]*x1 + Ki[4]*y1 + Ki[5]) * depth;
  float pzz = (Ki[6]*x1 + Ki[7]*y1 + Ki[8]) * depth;
  float X = P[0]*pxx + P[1]*pyy + P[2]*pzz + P[3];
  float Y = P[4]*pxx + P[5]*pyy + P[6]*pzz + P[7];
  float Z = P[8]*pxx + P[9]*pyy + P[10]*pzz + P[11];
  float q0 = Kc[0]*X + Kc[1]*Y + Kc[2]*Z;
  float q1 = Kc[3]*X + Kc[4]*Y + Kc[5]*Z;
  float q2 = Kc[6]*X + Kc[7]*Y + Kc[8]*Z;
  float iZc = 1.0f / fmaxf(q2, 0.01f);
  float ex = x2 - q0*iZc;
  float ey = y2 - q1*iZc;
  float iZ = 1.0f / fmaxf(Z, 1e-12f);
  float iZ2 = iZ*iZ;

  float jp0[6], jp1[6];
  jp0[0] = -(fx*iZ);  jp0[1] = 0.0f;       jp0[2] = fx*X*iZ2;
  jp0[3] = fx*X*Y*iZ2; jp0[4] = -(fx + fx*X*X*iZ2); jp0[5] = fx*Y*iZ;
  jp1[0] = 0.0f;      jp1[1] = -(fy*iZ);   jp1[2] = fy*Y*iZ2;
  jp1[3] = fy + fy*Y*Y*iZ2; jp1[4] = -(fy*X*Y*iZ2); jp1[5] = -(fy*X*iZ);

  float DD = -depth;
  float dx = X - P[3], dy = Y - P[7], dz = Z - P[11];
  float jd0 = -((fx*iZ)*(DD*dx) - (fx*X*iZ2)*(DD*dz));
  float jd1 = -((fy*iZ)*(DD*dy) - (fy*Y*iZ2)*(DD*dz));

  float en = sqrtf(ex*ex + ey*ey);
  float wmin = fminf(9.0f / fmaxf(en, 1e-12f), 1.0f);
  float w  = sqrtf(wmin) * m;
  float w2 = w * w;

  float dotE = 0.0f;
#pragma unroll
  for (int k = 0; k < 6; k++) {
    float Ek = w2*(jp0[k]*jd0 + jp1[k]*jd1);
    dotE += Ek * dp[k];
  }
  float C = w2*(jd0*jd0 + jd1*jd1);
  float cinv = 1.0f / fmaxf(C*onepL, 1.0f);
  float Wv = -w*(jd0*ex + jd1*ey);

  float dnew = d + cinv*(Wv - dotE*invL);
  dnew = fminf(fmaxf(dnew, 0.01f), 10.0f);

  float n1 = reproj_norm(x1, y1, x2, y2, dnew, Pn, Kc, Ki);
  float n2 = reproj_norm(x1, y1, x2, y2, d,    P,  Kc, Ki);
  r1a += n1*m; r2a += n2*m; msa += m;
  return dnew;
}

// solve: 54 sums -> dp[6] + pose_new[16]. Runs on one thread.
__device__ void solve_scalar(const float* S, float L, const float* Pc_in,
                             float invN, float* dp_out, float* Pn_out) {
  float Bm[6][6], Hs[6][6], g[6], bs[6];
  {
    int idx = 0;
    for (int k = 0; k < 6; k++)
      for (int l = k; l < 6; l++) { float v = S[idx++]*invN; Bm[k][l] = v; Bm[l][k] = v; }
    for (int k = 0; k < 6; k++) g[k] = S[21+k]*invN;
    idx = 27;
    for (int k = 0; k < 6; k++)
      for (int l = k; l < 6; l++) { float v = S[idx++]*invN; Hs[k][l] = v; Hs[l][k] = v; }
    for (int k = 0; k < 6; k++) bs[k] = S[48+k]*invN;
  }
  const float invL = 1.0f / (1.0f + L);
  float left[6][6], right[6];
  for (int k = 0; k < 6; k++) {
    for (int l = 0; l < 6; l++) {
      float v = Bm[k][l] - Hs[k][l]*invL;
      if (k == l) v += Bm[k][k]*L + 1.0f;
      left[k][l] = v;
    }
    right[k] = g[k] - bs[k]*invL;
  }
  float sv[6];
  for (int k = 0; k < 6; k++) sv[k] = 1.0f / sqrtf(left[k][k] + 10.0f);
  float H[6][7];
  for (int k = 0; k < 6; k++) {
    for (int l = 0; l < 6; l++) H[k][l] = sv[k]*left[k][l]*sv[l];
    H[k][6] = sv[k]*right[k];
  }
  for (int c = 0; c < 6; c++) {
    int piv = c; float mx = fabsf(H[c][c]);
    for (int r = c+1; r < 6; r++) { float a = fabsf(H[r][c]); if (a > mx) { mx = a; piv = r; } }
    if (piv != c)
      for (int cc2 = c; cc2 < 7; cc2++) { float tmp = H[c][cc2]; H[c][cc2] = H[piv][cc2]; H[piv][cc2] = tmp; }
    float ip = 1.0f / H[c][c];
    for (int r = c+1; r < 6; r++) {
      float f = H[r][c]*ip;
      for (int cc2 = c; cc2 < 7; cc2++) H[r][cc2] -= f*H[c][cc2];
    }
  }
  float x[6];
  for (int c = 5; c >= 0; c--) {
    float v = H[c][6];
    for (int cc2 = c+1; cc2 < 6; cc2++) v -= H[c][cc2]*x[cc2];
    x[c] = v / H[c][c];
  }
  float dp[6];
  for (int k = 0; k < 6; k++) { dp[k] = sv[k]*x[k]; dp_out[k] = dp[k]; }

  float tx = dp[0], ty = dp[1], tz = dp[2];
  float wx = dp[3], wy = dp[4], wz = dp[5];
  float Nr = fmaxf(sqrtf(wx*wx + wy*wy + wz*wz), 1e-12f);
  float rx = wx/Nr, ry = wy/Nr, rz = wz/Nr;
  float c_ = cosf(Nr), sn = sinf(Nr);
  float omc = 1.0f - c_;
  float SK[3][3] = {{0.0f,-rz,ry},{rz,0.0f,-rx},{-ry,rx,0.0f}};
  float SK2[3][3];
  for (int i = 0; i < 3; i++)
    for (int j2 = 0; j2 < 3; j2++) {
      float s2 = 0.0f;
      for (int k = 0; k < 3; k++) s2 += SK[i][k]*SK[k][j2];
      SK2[i][j2] = s2;
    }
  float rr[3] = {rx, ry, rz};
  float a = (Nr - sn)/Nr, bcoef = omc/Nr;
  float R3[3][3], Jm[3][3];
  for (int i = 0; i < 3; i++)
    for (int j2 = 0; j2 < 3; j2++) {
      float eye = (i == j2) ? 1.0f : 0.0f;
      R3[i][j2] = c_*eye + omc*rr[i]*rr[j2] + sn*SK[i][j2];
      Jm[i][j2] = eye + a*SK2[i][j2] + bcoef*SK[i][j2];
    }
  float T3[3];
  for (int i = 0; i < 3; i++) T3[i] = Jm[i][0]*tx + Jm[i][1]*ty + Jm[i][2]*tz;
  for (int i = 0; i < 3; i++)
    for (int j2 = 0; j2 < 4; j2++)
      Pn_out[i*4+j2] = R3[i][0]*Pc_in[j2] + R3[i][1]*Pc_in[4+j2] + R3[i][2]*Pc_in[8+j2] + T3[i]*Pc_in[12+j2];
  for (int j2 = 0; j2 < 4; j2++) Pn_out[12+j2] = Pc_in[12+j2];
}

// =================== cooperative single kernel ===================
__global__ __launch_bounds__(CT, 2) void kCoop(
    const float* __restrict__ pts, const float* __restrict__ disp0,
    const float* __restrict__ mask, const float* __restrict__ Kin,
    const float* __restrict__ Kiin, const float* __restrict__ pose0,
    const float* __restrict__ L0,
    float* __restrict__ partA, float* __restrict__ partB,
    float* __restrict__ dout, int N, int B) {
  cg::grid_group grid = cg::this_grid();
  const int b   = blockIdx.x / CBPB;
  const int bx  = blockIdx.x % CBPB;
  const int tid = threadIdx.x;
  const int lane = tid & 63, wvi = tid >> 6;

  __shared__ float sP[16];
  __shared__ float sPn[16];
  __shared__ float sdp[6];
  __shared__ float sS[NRED];
  __shared__ float sMeta[2]; // [0]=M, [1]=L
  __shared__ float lds54[CT/64][NRED];
  __shared__ float lds3[CT/64][3];

  float Kc[9], Ki[9];
#pragma unroll
  for (int i = 0; i < 9; i++) { Kc[i] = Kin[b*9+i]; Ki[i] = Kiin[b*9+i]; }
  const float fx = Kc[0], fy = Kc[4];

  if (tid == 0) {
#pragma unroll
    for (int i = 0; i < 16; i++) sP[i] = pose0[b*16+i];
    sMeta[0] = 0.0f; sMeta[1] = L0[b];
  }
  __syncthreads();

  const size_t bN = (size_t)b * N;
  const float* px1 = pts + (size_t)b*4*N;
  const float* py1 = px1 + N;
  const float* px2 = px1 + 2*(size_t)N;
  const float* py2 = px1 + 3*(size_t)N;
  const int n0 = bx*CT + tid;
  constexpr int STRIDE = CBPB*CT;

  // REGISTER-RESIDENT point data + disp state for this thread's 8 points.
  float rx1[CPPT], ry1[CPPT], rx2[CPPT], ry2[CPPT], rm[CPPT];
  float d[CPPT], dn[CPPT];
#pragma unroll
  for (int j = 0; j < CPPT; j++) {
    int n = n0 + j*STRIDE;
    bool ok = (n < N);
    rx1[j] = ok ? px1[n] : 0.0f;
    ry1[j] = ok ? py1[n] : 0.0f;
    rx2[j] = ok ? px2[n] : 0.0f;
    ry2[j] = ok ? py2[n] : 0.0f;
    rm[j]  = ok ? mask[bN+n] : 0.0f;
    d[j]   = ok ? disp0[bN+n] : 1.0f;
    dn[j]  = d[j];
  }

  for (int it = 0; it < 4; ++it) {
    if (it > 0) {
      if (tid == 0) {
        float r1 = 0.0f, r2 = 0.0f, ms = 0.0f;
        for (int j = 0; j < CBPB; j++) {
          const float* p = partB + ((size_t)b*CBPB + j)*3;
          r1 += p[0]; r2 += p[1]; ms += p[2];
        }
        float M = ((r1/ms) < (r2/ms)) ? 1.0f : 0.0f;
        sMeta[0] = M;
        float Lp = sMeta[1];
        float Ln = (M != 0.0f) ? Lp*0.5f : Lp*5.0f;
        sMeta[1] = fminf(fmaxf(Ln, 0.01f), 1000000.0f);
        if (M != 0.0f)
          for (int i = 0; i < 16; i++) sP[i] = sPn[i];
      }
      __syncthreads();
      if (sMeta[0] != 0.0f) {
#pragma unroll
        for (int j = 0; j < CPPT; j++) d[j] = dn[j];
      }
    }
    const float onepL = 1.0f + sMeta[1];
    float P[12];
#pragma unroll
    for (int i = 0; i < 12; i++) P[i] = sP[i];

    // phase A (no global loads)
    float acc[NRED];
#pragma unroll
    for (int k = 0; k < NRED; k++) acc[k] = 0.0f;
#pragma unroll
    for (int j = 0; j < CPPT; j++)
      pointA(rx1[j], ry1[j], rx2[j], ry2[j], rm[j], d[j],
             P, Kc, Ki, fx, fy, onepL, acc);
#pragma unroll
    for (int k = 0; k < NRED; k++) {
      float v = wave_red(acc[k]);
      if (lane == 0) lds54[wvi][k] = v;
    }
    __syncthreads();
    if (tid < NRED) {
      float s = 0.0f;
#pragma unroll
      for (int wq = 0; wq < CT/64; wq++) s += lds54[wq][tid];
      partA[((size_t)b*CBPB + bx)*NRED + tid] = s;
    }
    grid.sync();

    // solve prologue (redundant per block)
    if (tid < NRED) {
      float s = 0.0f;
      for (int j = 0; j < CBPB; j++)
        s += partA[((size_t)b*CBPB + j)*NRED + tid];
      sS[tid] = s;
    }
    __syncthreads();
    if (tid == 0) {
      float dpl[6], Pnl[16], Pcl[16], Sl[NRED];
      for (int i = 0; i < NRED; i++) Sl[i] = sS[i];
      for (int i = 0; i < 16; i++) Pcl[i] = sP[i];
      solve_scalar(Sl, sMeta[1], Pcl, 1.0f / (float)N, dpl, Pnl);
      for (int i = 0; i < 6; i++) sdp[i] = dpl[i];
      for (int i = 0; i < 16; i++) sPn[i] = Pnl[i];
    }
    __syncthreads();

    // phase B (no global loads)
    float Pn[12], dp[6];
#pragma unroll
    for (int i = 0; i < 12; i++) Pn[i] = sPn[i];
#pragma unroll
    for (int i = 0; i < 6; i++) dp[i] = sdp[i];
    const float invL = 1.0f / onepL;

    float r1a = 0.0f, r2a = 0.0f, msa = 0.0f;
#pragma unroll
    for (int j = 0; j < CPPT; j++)
      dn[j] = pointB(rx1[j], ry1[j], rx2[j], ry2[j], rm[j], d[j],
                     P, Pn, dp, Kc, Ki, fx, fy, onepL, invL, r1a, r2a, msa);
    {
      float v0 = wave_red(r1a), v1 = wave_red(r2a), v2 = wave_red(msa);
      if (lane == 0) { lds3[wvi][0] = v0; lds3[wvi][1] = v1; lds3[wvi][2] = v2; }
    }
    __syncthreads();
    if (tid < 3) {
      float s = 0.0f;
#pragma unroll
      for (int wq = 0; wq < CT/64; wq++) s += lds3[wq][tid];
      partB[((size_t)b*CBPB + bx)*3 + tid] = s;
    }
    grid.sync();
  }

  // final accept + output
  if (tid == 0) {
    float r1 = 0.0f, r2 = 0.0f, ms = 0.0f;
    for (int j = 0; j < CBPB; j++) {
      const float* p = partB + ((size_t)b*CBPB + j)*3;
      r1 += p[0]; r2 += p[1]; ms += p[2];
    }
    float M = ((r1/ms) < (r2/ms)) ? 1.0f : 0.0f;
    sMeta[0] = M;
    if (M != 0.0f)
      for (int i = 0; i < 16; i++) sP[i] = sPn[i];
  }
  __syncthreads();
  const float Mf = sMeta[0];

  if (bx == 0 && tid < 16) dout[b*16 + tid] = sP[tid];
  float* dd = dout + B*16;
#pragma unroll
  for (int j = 0; j < CPPT; j++) {
    int n = n0 + j*STRIDE;
    if (n < N) dd[bN+n] = (Mf != 0.0f) ? dn[j] : d[j];
  }
}

// =================== fallback: round-3 proven 9-dispatch path ===================
__device__ __forceinline__ float accept_M_fb(const float* __restrict__ partB, int b) {
  float r1 = 0.0f, r2 = 0.0f, ms = 0.0f;
  for (int j = 0; j < BLKA; j++) {
    const float* p = partB + ((size_t)b*BLKA + j)*3;
    r1 += p[0]; r2 += p[1]; ms += p[2];
  }
  return ((r1/ms) < (r2/ms)) ? 1.0f : 0.0f;
}

__global__ __launch_bounds__(TPB) void fb_kA(
    int it,
    const float* __restrict__ pts, const float* __restrict__ disp_src,
    const float* __restrict__ prop, const float* __restrict__ mask,
    const float* __restrict__ Kin, const float* __restrict__ Kiin,
    float* __restrict__ disp_cur,
    const float* __restrict__ pose0, const float* __restrict__ L0,
    const float* __restrict__ partB, const float* __restrict__ pose_new_ws,
    float* __restrict__ pose_slot_w, const float* __restrict__ pose_slot_r,
    float* __restrict__ L_slot_w, const float* __restrict__ L_slot_r,
    float* __restrict__ partA, int N) {
  const int b = blockIdx.y;

  __shared__ float sP[16];
  __shared__ float sMeta[2];
  if (threadIdx.x == 0) {
    float P[16], Lv, fs;
    if (it == 0) {
      for (int i = 0; i < 16; i++) P[i] = pose0[b*16+i];
      Lv = L0[b]; fs = 0.0f;
    } else {
      float M = accept_M_fb(partB, b);
      fs = M;
      float Lp = L_slot_r[b];
      float Ln = (M != 0.0f) ? Lp*0.5f : Lp*5.0f;
      Lv = fminf(fmaxf(Ln, 0.01f), 1000000.0f);
      for (int i = 0; i < 16; i++)
        P[i] = (M != 0.0f) ? pose_new_ws[b*16+i] : pose_slot_r[b*16+i];
    }
    for (int i = 0; i < 16; i++) sP[i] = P[i];
    sMeta[0] = fs; sMeta[1] = Lv;
    if (blockIdx.x == 0) {
      for (int i = 0; i < 16; i++) pose_slot_w[b*16+i] = P[i];
      L_slot_w[b] = Lv;
    }
  }
  __syncthreads();

  float Kc[9], Ki[9], P[12];
#pragma unroll
  for (int i = 0; i < 9; i++) { Kc[i] = Kin[b*9+i]; Ki[i] = Kiin[b*9+i]; }
#pragma unroll
  for (int i = 0; i < 12; i++) P[i] = sP[i];
  const float onepL = 1.0f + sMeta[1];
  const float fsel = sMeta[0];
  const float fx = Kc[0], fy = Kc[4];

  float acc[NRED];
#pragma unroll
  for (int k = 0; k < NRED; k++) acc[k] = 0.0f;

  const size_t bN = (size_t)b * N;
  const float* px1 = pts + (size_t)b*4*N;
  const float* py1 = px1 + N;
  const float* px2 = px1 + 2*(size_t)N;
  const float* py2 = px1 + 3*(size_t)N;

  for (int n = blockIdx.x*TPB + threadIdx.x; n < N; n += gridDim.x*TPB) {
    float x1 = px1[n], y1 = py1[n], x2 = px2[n], y2 = py2[n];
    float d = disp_src[bN+n];
    if (fsel != 0.0f) d = prop[bN+n];
    disp_cur[bN+n] = d;
    float m = mask[bN+n];
    pointA(x1, y1, x2, y2, m, d, P, Kc, Ki, fx, fy, onepL, acc);
  }

  __shared__ float lds[TPB/64][NRED];
  const int lane = threadIdx.x & 63, wvi = threadIdx.x >> 6;
#pragma unroll
  for (int k = 0; k < NRED; k++) {
    float v = wave_red(acc[k]);
    if (lane == 0) lds[wvi][k] = v;
  }
  __syncthreads();
  if (threadIdx.x < NRED) {
    float s = 0.0f;
#pragma unroll
    for (int wq = 0; wq < TPB/64; wq++) s += lds[wq][threadIdx.x];
    partA[((size_t)b*gridDim.x + blockIdx.x)*NRED + threadIdx.x] = s;
  }
}

__global__ __launch_bounds__(TPB) void fb_kB(
    const float* __restrict__ pts, const float* __restrict__ disp_cur,
    const float* __restrict__ mask,
    const float* __restrict__ Kin, const float* __restrict__ Kiin,
    const float* __restrict__ pose_slot, const float* __restrict__ L_slot,
    const float* __restrict__ partA,
    float* __restrict__ pose_new_ws,
    float* __restrict__ prop, float* __restrict__ partB, int N) {
  const int b = blockIdx.y;
  const float L = L_slot[b];

  __shared__ float S[NRED];
  __shared__ float sPn[16];
  __shared__ float sdp[6];
  if (threadIdx.x < NRED) {
    float s = 0.0f;
    for (int j = 0; j < BLKA; j++)
      s += partA[((size_t)b*BLKA + j)*NRED + threadIdx.x];
    S[threadIdx.x] = s;
  }
  __syncthreads();
  if (threadIdx.x == 0) {
    float dpl[6], Pnl[16], Pcl[16], Sl[NRED];
    for (int i = 0; i < NRED; i++) Sl[i] = S[i];
    for (int i = 0; i < 16; i++) Pcl[i] = pose_slot[b*16+i];
    solve_scalar(Sl, L, Pcl, 1.0f / (float)N, dpl, Pnl);
    for (int i = 0; i < 6; i++) sdp[i] = dpl[i];
    for (int i = 0; i < 16; i++) sPn[i] = Pnl[i];
    if (blockIdx.x == 0)
      for (int i = 0; i < 16; i++) pose_new_ws[b*16+i] = Pnl[i];
  }
  __syncthreads();

  float Kc[9], Ki[9], P[12], Pn[12], dp[6];
#pragma unroll
  for (int i = 0; i < 9; i++) { Kc[i] = Kin[b*9+i]; Ki[i] = Kiin[b*9+i]; }
#pragma unroll
  for (int i = 0; i < 12; i++) { P[i] = pose_slot[b*16+i]; Pn[i] = sPn[i]; }
#pragma unroll
  for (int i = 0; i < 6; i++) dp[i] = sdp[i];
  const float onepL = 1.0f + L;
  const float invL = 1.0f / onepL;
  const float fx = Kc[0], fy = Kc[4];

  float r1a = 0.0f, r2a = 0.0f, msa = 0.0f;
  const size_t bN = (size_t)b * N;
  const float* px1 = pts + (size_t)b*4*N;
  const float* py1 = px1 + N;
  const float* px2 = px1 + 2*(size_t)N;
  const float* py2 = px1 + 3*(size_t)N;

  for (int n = blockIdx.x*TPB + threadIdx.x; n < N; n += gridDim.x*TPB) {
    float x1 = px1[n], y1 = py1[n], x2 = px2[n], y2 = py2[n];
    float d = disp_cur[bN+n];
    float m = mask[bN+n];
    float dnew = pointB(x1, y1, x2, y2, m, d, P, Pn, dp, Kc, Ki,
                        fx, fy, onepL, invL, r1a, r2a, msa);
    prop[bN+n] = dnew;
  }

  __shared__ float lds[TPB/64][3];
  const int lane = threadIdx.x & 63, wvi = threadIdx.x >> 6;
  float v0 = wave_red(r1a), v1 = wave_red(r2a), v2 = wave_red(msa);
  if (lane == 0) { lds[wvi][0] = v0; lds[wvi][1] = v1; lds[wvi][2] = v2; }
  __syncthreads();
  if (threadIdx.x < 3) {
    float s = 0.0f;
#pragma unroll
    for (int wq = 0; wq < TPB/64; wq++) s += lds[wq][threadIdx.x];
    partB[((size_t)b*gridDim.x + blockIdx.x)*3 + threadIdx.x] = s;
  }
}

__global__ __launch_bounds__(TPB) void fb_kF(
    const float* __restrict__ partB,
    const float* __restrict__ pose_slot, const float* __restrict__ pose_new_ws,
    const float* __restrict__ prop, float* __restrict__ dout, int N, int B) {
  const int b = blockIdx.y;
  __shared__ float sM[1];
  if (threadIdx.x == 0) sM[0] = accept_M_fb(partB, b);
  __syncthreads();
  const float M = sM[0];

  if (blockIdx.x == 0 && threadIdx.x < 16) {
    float v = (M != 0.0f) ? pose_new_ws[b*16+threadIdx.x] : pose_slot[b*16+threadIdx.x];
    dout[b*16 + threadIdx.x] = v;
  }
  if (M == 0.0f) return;
  float* dd = dout + B*16;
  const size_t bN = (size_t)b * N;
  for (int n = blockIdx.x*TPB + threadIdx.x; n < N; n += gridDim.x*TPB)
    dd[bN+n] = prop[bN+n];
}

extern "C" void kernel_launch(void* const* d_in, const int* in_sizes, int n_in,
                              void* d_out, int out_size, void* d_ws, size_t ws_size,
                              hipStream_t stream) {
  const float* pts   = (const float*)d_in[0];
  const float* disp0 = (const float*)d_in[1];
  const float* pose0 = (const float*)d_in[2];
  const float* Kin   = (const float*)d_in[3];
  const float* Kiin  = (const float*)d_in[4];
  const float* mask  = (const float*)d_in[5];
  const float* L0    = (const float*)d_in[6];

  const int B = in_sizes[6];            // 8
  const int N = in_sizes[1] / B;        // 131072
  const size_t BN = (size_t)B * N;

  float* out      = (float*)d_out;
  float* disp_cur = out + B*16;

  // ws layout: fallback region first, coop region after (disjoint).
  float* ws        = (float*)d_ws;
  float* prop      = ws;                                   // BN
  float* partA_fb  = prop + BN;                            // B*BLKA*NRED
  float* partB_fb  = partA_fb + (size_t)B*BLKA*NRED;       // B*BLKA*3
  float* pose_slots= partB_fb + (size_t)B*BLKA*3;          // 2*B*16
  float* pose_new  = pose_slots + (size_t)2*B*16;          // B*16
  float* L_slots   = pose_new + (size_t)B*16;              // 2*B
  float* partA_cp  = L_slots + (size_t)2*B;                // B*CBPB*NRED
  float* partB_cp  = partA_cp + (size_t)B*CBPB*NRED;       // B*CBPB*3

  // ---- try cooperative single-kernel path ----
  void* args[] = {(void*)&pts, (void*)&disp0, (void*)&mask, (void*)&Kin,
                  (void*)&Kiin, (void*)&pose0, (void*)&L0,
                  (void*)&partA_cp, (void*)&partB_cp, (void*)&out,
                  (void*)&N, (void*)&B};
  hipError_t ce = hipLaunchCooperativeKernel((void*)kCoop, dim3(B*CBPB),
                                             dim3(CT), args, 0, stream);
  if (ce == hipSuccess) return;
  (void)hipGetLastError();   // clear latched error, run proven fallback

  dim3 gridBig(BLKA, B), blk(TPB);
  for (int it = 0; it < 4; ++it) {
    float* ps_w = pose_slots + (size_t)(it & 1) * B * 16;
    const float* ps_r = pose_slots + (size_t)((it + 1) & 1) * B * 16;
    float* Ls_w = L_slots + (size_t)(it & 1) * B;
    const float* Ls_r = L_slots + (size_t)((it + 1) & 1) * B;

    fb_kA<<<gridBig, blk, 0, stream>>>(it, pts, (it == 0) ? disp0 : disp_cur, prop,
                                       mask, Kin, Kiin, disp_cur, pose0, L0,
                                       partB_fb, pose_new, ps_w, ps_r, Ls_w, Ls_r,
                                       partA_fb, N);
    fb_kB<<<gridBig, blk, 0, stream>>>(pts, disp_cur, mask, Kin, Kiin,
                                       ps_w, Ls_w, partA_fb, pose_new,
                                       prop, partB_fb, N);
  }
  fb_kF<<<gridBig, blk, 0, stream>>>(partB_fb, pose_slots + (size_t)1*B*16,
                                     pose_new, prop, out, N, B);
}